// Round 13
// baseline (171.537 us; speedup 1.0000x reference)
//
#include <hip/hip_runtime.h>

#define S_LEN 2048
#define D_MODEL 1024
#define DH 64      // head dim
#define BQ 128     // q rows per block (32 per wave)
#define BK 128     // keys per k-tile
#define ZSCALE 0.18033688f   // 0.125 * log2(e) — folded into Q fragments

using short8 = __attribute__((ext_vector_type(8))) short;
using s4v    = __attribute__((ext_vector_type(4))) short;
using f32x4  = __attribute__((ext_vector_type(4))) float;
using u32x4  = __attribute__((ext_vector_type(4))) unsigned int;

#define BMM(a, b, c) __builtin_amdgcn_mfma_f32_16x16x32_bf16((a), (b), (c), 0, 0, 0)
#define LGKM_BAR() do { asm volatile("s_waitcnt lgkmcnt(0)" ::: "memory"); \
                        __builtin_amdgcn_s_barrier(); \
                        __builtin_amdgcn_sched_barrier(0); } while (0)

__device__ __forceinline__ unsigned short f2bf(float x) {
    union { float f; unsigned int u; } c; c.f = x;
    unsigned int u = c.u;
    u += 0x7fffu + ((u >> 16) & 1u);   // RNE
    return (unsigned short)(u >> 16);
}

// ---- fused converter (verified) ----
__global__ __launch_bounds__(256) void cvt_fused(const float* __restrict__ V,
                                                 const int* __restrict__ M,
                                                 const float* __restrict__ K,
                                                 unsigned short* __restrict__ VT,
                                                 unsigned long long* __restrict__ Mb,
                                                 unsigned short* __restrict__ KB) {
    const int blk = blockIdx.x;
    const int tid = threadIdx.x;
    if (blk < 1024) {
        __shared__ float tsF[64][65];
        const int b  = blk >> 9;
        const int h  = (blk >> 5) & 15;
        const int s0 = (blk & 31) * 64;
        #pragma unroll
        for (int it = 0; it < 2; ++it) {
            int seg = tid + it * 256;
            int s = seg >> 3, d8 = (seg & 7) << 3;
            const float* p = V + (size_t)(b * S_LEN + s0 + s) * D_MODEL + h * DH + d8;
            f32x4 a = *(const f32x4*)p;
            f32x4 c = *(const f32x4*)(p + 4);
            #pragma unroll
            for (int j = 0; j < 4; ++j) { tsF[s][d8 + j] = a[j]; tsF[s][d8 + 4 + j] = c[j]; }
        }
        __syncthreads();
        #pragma unroll
        for (int it = 0; it < 2; ++it) {
            int seg = tid + it * 256;
            int d = seg >> 3, s8 = (seg & 7) << 3;
            short8 w;
            #pragma unroll
            for (int j = 0; j < 8; ++j) w[j] = (short)f2bf(tsF[s8 + j][d]);
            *(short8*)(VT + ((size_t)((b * 16 + h) * 64 + d)) * S_LEN + s0 + s8) = w;
        }
    } else if (blk < 2048) {
        const int pb   = blk - 1024;
        const int wave = tid >> 6, lane = tid & 63;
        const int row  = pb * 4 + wave;
        const int* mp  = M + (size_t)row * S_LEN;
        #pragma unroll 4
        for (int it = 0; it < 32; ++it) {
            int m = mp[it * 64 + lane];
            unsigned long long bal = __ballot(m != 0);
            if (lane == 0) Mb[(size_t)row * 32 + it] = bal;
        }
    } else {
        size_t base = (size_t)(blk - 2048) * 4096;
        #pragma unroll
        for (int it = 0; it < 4; ++it) {
            size_t i = base + ((size_t)(it * 256 + tid)) * 4;
            f32x4 a = *(const f32x4*)(K + i);
            s4v w;
            #pragma unroll
            for (int j = 0; j < 4; ++j) w[j] = (short)f2bf(a[j]);
            *(s4v*)(KB + i) = w;
        }
    }
}

// ---- main kernel v16 = v15 arithmetic (swizzled LDS, conflicts=0) with:
//  (a) K/V double-buffered (64 KB) -> ONE barrier per tile.  Barrier at end of
//      body t certifies both "buf[t+1] writes visible" and "all waves finished
//      reading buf[t-1]" (they passed their compute before this barrier).
//  (b) 2-unrolled loop with A/B register sets -> zero rotation movs.
//  (c) stage ds_writes spread through the compute region (after each PVKC).
__global__ __launch_bounds__(256) void mha_fwd_v16(
    const float* __restrict__ Q,
    const float* __restrict__ K,             // f32 (used when KB == 0)
    const unsigned short* __restrict__ KB,   // bf16 preconverted (may be null)
    const unsigned short* __restrict__ VT,   // bf16 pre-transposed [d][s]
    const unsigned long long* __restrict__ Mb, // packed mask u64, 32/row
    float* __restrict__ O,
    int kbf)
{
    __shared__ alignas(16) unsigned short Ks[2][BK][64];   // 2x16 KB
    __shared__ alignas(16) unsigned short Vt[2][DH][128];  // 2x16 KB

    // XCD-chunked swizzle: nwg=512, 8 XCDs -> each XCD gets 64 contiguous blk
    const int blk0 = blockIdx.x;
    const int blk  = ((blk0 & 7) << 6) | (blk0 >> 3);

    const int b   = blk >> 8;
    const int h   = (blk >> 4) & 15;
    const int qbase = (blk & 15) * BQ;
    const int bh  = b * 16 + h;

    const int tid  = threadIdx.x;
    const int wave = tid >> 6;
    const int lane = tid & 63;
    const int n16  = lane & 15;
    const int quad = lane >> 4;
    const int bq   = quad << 3;          // mask half-word shift
    const int n7   = n16 & 7;

    // K staging: 256 thr cover 32 rows x 64 cols per round (4 rounds), sigma rows
    const int srow = tid >> 3;
    const int prow = (((srow >> 2) & 1) << 4) | (((srow >> 3) & 3) << 2) | (srow & 3);
    // V staging: 256 thr cover 16 rows x 128 cols per round (4 rounds)
    const int vrow = tid >> 4;

    // LDS XOR-swizzle columns (16B granules; phys = logical ^ (row & (ng-1)))
    const int kwcol = (((tid & 7) ^ (prow & 7)) << 3);
    const int vwcol = (((tid & 15) ^ vrow) << 3);
    const int krc0  = ((quad ^ n7) << 3);
    const int krc1  = krc0 ^ 32;
    int vrc[4];
    #pragma unroll
    for (int kc = 0; kc < 4; ++kc) vrc[kc] = (((kc * 4 + quad) ^ n16) << 3);

    // Q fragments (B operand), PRE-SCALED by ZSCALE
    short8 qf[2][2];
    #pragma unroll
    for (int qg = 0; qg < 2; ++qg) {
        const size_t qoff = (size_t)(b * S_LEN + qbase + wave * 32 + qg * 16 + n16) * D_MODEL
                          + h * DH + quad * 8;
        f32x4 a0 = *(const f32x4*)(Q + qoff);
        f32x4 a1 = *(const f32x4*)(Q + qoff + 4);
        f32x4 a2 = *(const f32x4*)(Q + qoff + 32);
        f32x4 a3 = *(const f32x4*)(Q + qoff + 36);
        short8 q0, q1;
        #pragma unroll
        for (int j = 0; j < 4; ++j) {
            q0[j] = (short)f2bf(a0[j] * ZSCALE); q0[4 + j] = (short)f2bf(a1[j] * ZSCALE);
            q1[j] = (short)f2bf(a2[j] * ZSCALE); q1[4 + j] = (short)f2bf(a3[j] * ZSCALE);
        }
        qf[qg][0] = q0; qf[qg][1] = q1;
    }

    const short8 ones = {0x3F80,0x3F80,0x3F80,0x3F80,0x3F80,0x3F80,0x3F80,0x3F80}; // bf16 1.0

    f32x4 o[2][4], o4[2];
    #pragma unroll
    for (int qg = 0; qg < 2; ++qg) {
        #pragma unroll
        for (int dg = 0; dg < 4; ++dg) o[qg][dg] = f32x4{0.f,0.f,0.f,0.f};
        o4[qg] = f32x4{0.f,0.f,0.f,0.f};
    }

    const unsigned long long* mrow[2];
    #pragma unroll
    for (int qg = 0; qg < 2; ++qg)
        mrow[qg] = Mb + (size_t)(b * S_LEN + qbase + wave * 32 + qg * 16 + n16) * 32;

    const size_t kbase = (size_t)(b * S_LEN) * D_MODEL + h * DH;
    const size_t vbase = (size_t)(bh * 64) * S_LEN;

    // A/B register sets (even/odd tiles); zero rotation
    short8 kaA[4], vaA[4], kaB[4], vaB[4];
    unsigned long long mwA[2][2], mwB[2][2];

    auto LD = [&](int kb2, short8 (&ka)[4], short8 (&va)[4], unsigned long long (&mw)[2][2]) {
        if (kbf) {
            #pragma unroll
            for (int i = 0; i < 4; ++i)
                ka[i] = *(const short8*)(KB + kbase + (size_t)(kb2 + i * 32 + srow) * D_MODEL + ((tid & 7) << 3));
        } else {
            #pragma unroll
            for (int i = 0; i < 4; ++i) {
                const float* kp = K + kbase + (size_t)(kb2 + i * 32 + srow) * D_MODEL + ((tid & 7) << 3);
                f32x4 p0 = *(const f32x4*)kp, p1 = *(const f32x4*)(kp + 4);
                short8 w;
                #pragma unroll
                for (int j = 0; j < 4; ++j) { w[j] = (short)f2bf(p0[j]); w[4 + j] = (short)f2bf(p1[j]); }
                ka[i] = w;
            }
        }
        #pragma unroll
        for (int i = 0; i < 4; ++i)   // VT is [d][s]: tile offset on the COLUMN
            va[i] = *(const short8*)(VT + vbase + (size_t)(vrow + 16 * i) * S_LEN + kb2 + ((tid & 15) << 3));
        const int wi = kb2 >> 6;
        #pragma unroll
        for (int qg = 0; qg < 2; ++qg) { mw[qg][0] = mrow[qg][wi]; mw[qg][1] = mrow[qg][wi + 1]; }
    };
    auto MKAM = [&](unsigned long long (&mw)[2][2], unsigned int (&am)[2][4]) {
        #pragma unroll
        for (int qg = 0; qg < 2; ++qg) {
            am[qg][0] = ((unsigned int)mw[qg][0]) >> bq;
            am[qg][1] = ((unsigned int)(mw[qg][0] >> 32)) >> bq;
            am[qg][2] = ((unsigned int)mw[qg][1]) >> bq;
            am[qg][3] = ((unsigned int)(mw[qg][1] >> 32)) >> bq;
        }
    };
    auto QKCT = [&](int pb, int ct, unsigned int (&am)[2][4], u32x4 (&Af)[2][4]) {
        short8 kf0 = *(const short8*)&Ks[pb][ct * 16 + n16][krc0];
        short8 kf1 = *(const short8*)&Ks[pb][ct * 16 + n16][krc1];
        f32x4 sA = {0.f,0.f,0.f,0.f}, sB = sA;
        sA = BMM(kf0, qf[0][0], sA); sA = BMM(kf1, qf[0][1], sA);
        sB = BMM(kf0, qf[1][0], sB); sB = BMM(kf1, qf[1][1], sB);
        unsigned int puA[4], puB[4];
        #pragma unroll
        for (int r = 0; r < 4; ++r) {
            puA[r] = __float_as_uint(__builtin_amdgcn_exp2f(sA[r]));
            puB[r] = __float_as_uint(__builtin_amdgcn_exp2f(sB[r]));
        }
        const int sel = ct >> 1, sb = (ct & 1) * 4, kc = ct >> 1, ub = (ct & 1) * 2;
        unsigned int nibA = (am[0][sel] >> sb) & 0xFu;
        unsigned int nibB = (am[1][sel] >> sb) & 0xFu;
        unsigned int m8A = ((nibA * 0x00204081u) & 0x01010101u) * 0xFFu;
        unsigned int m8B = ((nibB * 0x00204081u) & 0x01010101u) * 0xFFu;
        Af[0][kc][ub + 0] = __builtin_amdgcn_perm(puA[1], puA[0], 0x07060302u)
                          & __builtin_amdgcn_perm(0u, m8A, 0x01010000u);
        Af[0][kc][ub + 1] = __builtin_amdgcn_perm(puA[3], puA[2], 0x07060302u)
                          & __builtin_amdgcn_perm(0u, m8A, 0x03030202u);
        Af[1][kc][ub + 0] = __builtin_amdgcn_perm(puB[1], puB[0], 0x07060302u)
                          & __builtin_amdgcn_perm(0u, m8B, 0x01010000u);
        Af[1][kc][ub + 1] = __builtin_amdgcn_perm(puB[3], puB[2], 0x07060302u)
                          & __builtin_amdgcn_perm(0u, m8B, 0x03030202u);
    };
    auto PVKC = [&](int pb, int kc, u32x4 (&Af)[2][4]) {
        short8 v0 = *(const short8*)&Vt[pb][      n16][vrc[kc]];
        short8 v1 = *(const short8*)&Vt[pb][16 + n16][vrc[kc]];
        short8 v2 = *(const short8*)&Vt[pb][32 + n16][vrc[kc]];
        short8 v3 = *(const short8*)&Vt[pb][48 + n16][vrc[kc]];
        union { u32x4 u; short8 s; } c0, c1;
        c0.u = Af[0][kc]; c1.u = Af[1][kc];
        o[0][0] = BMM(c0.s, v0, o[0][0]); o[0][1] = BMM(c0.s, v1, o[0][1]);
        o[0][2] = BMM(c0.s, v2, o[0][2]); o[0][3] = BMM(c0.s, v3, o[0][3]);
        o4[0]   = BMM(c0.s, ones, o4[0]);
        o[1][0] = BMM(c1.s, v0, o[1][0]); o[1][1] = BMM(c1.s, v1, o[1][1]);
        o[1][2] = BMM(c1.s, v2, o[1][2]); o[1][3] = BMM(c1.s, v3, o[1][3]);
        o4[1]   = BMM(c1.s, ones, o4[1]);
    };
    auto STG = [&](int pb, short8 (&ka)[4], short8 (&va)[4], int i) {
        *(short8*)&Ks[pb][prow + 32 * i][kwcol] = ka[i];
        *(short8*)&Vt[pb][vrow + 16 * i][vwcol] = va[i];
    };
    // body: compute tile in buf pb (mask mwC), optionally load next-next tile
    // into (lka,lva,lmw), optionally stage (ska,sva) into buf pb^1
    auto BODY = [&](int pb, unsigned long long (&mwC)[2][2],
                    int ldkb, short8 (&lka)[4], short8 (&lva)[4],
                    unsigned long long (&lmw)[2][2], bool doLoad,
                    short8 (&ska)[4], short8 (&sva)[4], bool doStage) {
        unsigned int am[2][4]; MKAM(mwC, am);     // before LD overwrites lmw(=mwC)
        if (doLoad) LD(ldkb, lka, lva, lmw);
        u32x4 Af[2][4];
        __builtin_amdgcn_s_setprio(1);
        QKCT(pb, 0, am, Af); QKCT(pb, 1, am, Af); PVKC(pb, 0, Af);
        if (doStage) STG(pb ^ 1, ska, sva, 0);
        QKCT(pb, 2, am, Af); QKCT(pb, 3, am, Af); PVKC(pb, 1, Af);
        if (doStage) STG(pb ^ 1, ska, sva, 1);
        QKCT(pb, 4, am, Af); QKCT(pb, 5, am, Af); PVKC(pb, 2, Af);
        if (doStage) STG(pb ^ 1, ska, sva, 2);
        QKCT(pb, 6, am, Af); QKCT(pb, 7, am, Af); PVKC(pb, 3, Af);
        if (doStage) STG(pb ^ 1, ska, sva, 3);
        __builtin_amdgcn_s_setprio(0);
    };

    // ---- prologue: tile0 -> buf0; tile1 -> B-regs ----
    LD(0, kaA, vaA, mwA);
    #pragma unroll
    for (int i = 0; i < 4; ++i) STG(0, kaA, vaA, i);
    LD(BK, kaB, vaB, mwB);
    LGKM_BAR();

    // ---- main: tiles 0..13 (loads reach tile 15) ----
    for (int it = 0; it < 7; ++it) {
        BODY(0, mwA, (2 * it + 2) * BK, kaA, vaA, mwA, true, kaB, vaB, true);
        LGKM_BAR();
        BODY(1, mwB, (2 * it + 3) * BK, kaB, vaB, mwB, true, kaA, vaA, true);
        LGKM_BAR();
    }
    // ---- t=14: compute buf0, stage buf1 <- B(t15), no load ----
    BODY(0, mwA, 0, kaA, vaA, mwA, false, kaB, vaB, true);
    LGKM_BAR();
    // ---- t=15: compute buf1 only ----
    BODY(1, mwB, 0, kaB, vaB, mwB, false, kaA, vaA, false);

    // epilogue: normalize by MFMA row sums, store f32 (row=quad*4+r, col=n16)
    #pragma unroll
    for (int qg = 0; qg < 2; ++qg) {
        #pragma unroll
        for (int r = 0; r < 4; ++r) {
            float rl = 1.f / o4[qg][r];
            size_t row = (size_t)(b * S_LEN + qbase + wave * 32 + qg * 16 + quad * 4 + r);
            float* op = O + row * D_MODEL + h * DH + n16;
            op[0]  = o[qg][0][r] * rl;
            op[16] = o[qg][1][r] * rl;
            op[32] = o[qg][2][r] * rl;
            op[48] = o[qg][3][r] * rl;
        }
    }
}

extern "C" void kernel_launch(void* const* d_in, const int* in_sizes, int n_in,
                              void* d_out, int out_size, void* d_ws, size_t ws_size,
                              hipStream_t stream) {
    const float* Q = (const float*)d_in[0];
    const float* K = (const float*)d_in[1];
    const float* V = (const float*)d_in[2];
    const int*   M = (const int*)d_in[3];
    float*       O = (float*)d_out;

    const size_t NEL = (size_t)2 * S_LEN * D_MODEL;            // 4,194,304
    const size_t VT_BYTES = NEL * sizeof(unsigned short);      // 8 MB
    const size_t KB_BYTES = NEL * sizeof(unsigned short);      // 8 MB
    const size_t MB_BYTES = (size_t)2 * S_LEN * 32 * 8;        // 1 MB

    if (ws_size >= VT_BYTES + KB_BYTES + MB_BYTES) {           // 17 MB: full precompute
        unsigned short* VT = (unsigned short*)d_ws;
        unsigned short* KB = (unsigned short*)((char*)d_ws + VT_BYTES);
        unsigned long long* Mb = (unsigned long long*)((char*)d_ws + VT_BYTES + KB_BYTES);
        hipLaunchKernelGGL(cvt_fused, dim3(3072), dim3(256), 0, stream, V, M, K, VT, Mb, KB);
        hipLaunchKernelGGL(mha_fwd_v16, dim3(512), dim3(256), 0, stream,
                           Q, K, KB, VT, Mb, O, 1);
    } else {                                                   // 9 MB: inline K convert
        unsigned short* VT = (unsigned short*)d_ws;
        unsigned long long* Mb = (unsigned long long*)((char*)d_ws + VT_BYTES);
        hipLaunchKernelGGL(cvt_fused, dim3(2048), dim3(256), 0, stream, V, M, K, VT, Mb, (unsigned short*)0);
        hipLaunchKernelGGL(mha_fwd_v16, dim3(512), dim3(256), 0, stream,
                           Q, K, (const unsigned short*)0, VT, Mb, O, 0);
    }
}

// Round 14
// 171.496 us; speedup vs baseline: 1.0002x; 1.0002x over previous
//
#include <hip/hip_runtime.h>

#define S_LEN 2048
#define D_MODEL 1024
#define DH 64      // head dim
#define BQ 128     // q rows per block (32 per wave)
#define BK 128     // keys per k-tile
#define ZSCALE 0.18033688f   // 0.125 * log2(e) — folded into Q fragments

using short8 = __attribute__((ext_vector_type(8))) short;
using s4v    = __attribute__((ext_vector_type(4))) short;
using f32x4  = __attribute__((ext_vector_type(4))) float;
using u32x4  = __attribute__((ext_vector_type(4))) unsigned int;

#define BMM(a, b, c) __builtin_amdgcn_mfma_f32_16x16x32_bf16((a), (b), (c), 0, 0, 0)
#define FULL_BAR() do { asm volatile("s_waitcnt vmcnt(0) lgkmcnt(0)" ::: "memory"); \
                        __builtin_amdgcn_s_barrier(); \
                        __builtin_amdgcn_sched_barrier(0); } while (0)

typedef const __attribute__((address_space(1))) unsigned int* gas1_t;
typedef __attribute__((address_space(3))) unsigned int* las3_t;

__device__ __forceinline__ unsigned short f2bf(float x) {
    union { float f; unsigned int u; } c; c.f = x;
    unsigned int u = c.u;
    u += 0x7fffu + ((u >> 16) & 1u);   // RNE
    return (unsigned short)(u >> 16);
}

// ---- fused converter (verified) ----
__global__ __launch_bounds__(256) void cvt_fused(const float* __restrict__ V,
                                                 const int* __restrict__ M,
                                                 const float* __restrict__ K,
                                                 unsigned short* __restrict__ VT,
                                                 unsigned long long* __restrict__ Mb,
                                                 unsigned short* __restrict__ KB) {
    const int blk = blockIdx.x;
    const int tid = threadIdx.x;
    if (blk < 1024) {
        __shared__ float tsF[64][65];
        const int b  = blk >> 9;
        const int h  = (blk >> 5) & 15;
        const int s0 = (blk & 31) * 64;
        #pragma unroll
        for (int it = 0; it < 2; ++it) {
            int seg = tid + it * 256;
            int s = seg >> 3, d8 = (seg & 7) << 3;
            const float* p = V + (size_t)(b * S_LEN + s0 + s) * D_MODEL + h * DH + d8;
            f32x4 a = *(const f32x4*)p;
            f32x4 c = *(const f32x4*)(p + 4);
            #pragma unroll
            for (int j = 0; j < 4; ++j) { tsF[s][d8 + j] = a[j]; tsF[s][d8 + 4 + j] = c[j]; }
        }
        __syncthreads();
        #pragma unroll
        for (int it = 0; it < 2; ++it) {
            int seg = tid + it * 256;
            int d = seg >> 3, s8 = (seg & 7) << 3;
            short8 w;
            #pragma unroll
            for (int j = 0; j < 8; ++j) w[j] = (short)f2bf(tsF[s8 + j][d]);
            *(short8*)(VT + ((size_t)((b * 16 + h) * 64 + d)) * S_LEN + s0 + s8) = w;
        }
    } else if (blk < 2048) {
        const int pb   = blk - 1024;
        const int wave = tid >> 6, lane = tid & 63;
        const int row  = pb * 4 + wave;
        const int* mp  = M + (size_t)row * S_LEN;
        #pragma unroll 4
        for (int it = 0; it < 32; ++it) {
            int m = mp[it * 64 + lane];
            unsigned long long bal = __ballot(m != 0);
            if (lane == 0) Mb[(size_t)row * 32 + it] = bal;
        }
    } else {
        size_t base = (size_t)(blk - 2048) * 4096;
        #pragma unroll
        for (int it = 0; it < 4; ++it) {
            size_t i = base + ((size_t)(it * 256 + tid)) * 4;
            f32x4 a = *(const f32x4*)(K + i);
            s4v w;
            #pragma unroll
            for (int j = 0; j < 4; ++j) w[j] = (short)f2bf(a[j]);
            *(s4v*)(KB + i) = w;
        }
    }
}

// ---- main kernel v17 = v16 numerics/layout (swizzled dbuf LDS, conflicts=0),
//      staging via __builtin_amdgcn_global_load_lds (kbf=1): LDS dest LINEAR,
//      sigma^-1 + XOR pre-applied to the per-lane GLOBAL source (m173 pattern;
//      rule #21 both-sides).  Deletes 8 global-loads + 8 ds_writes + 32 VGPR
//      from each wave's per-tile issue stream.  Compute = v14's best-measured
//      grouping.  One vmcnt+lgkm barrier per tile.
__global__ __launch_bounds__(256) void mha_fwd_v17(
    const float* __restrict__ Q,
    const float* __restrict__ K,             // f32 (used when KB == 0)
    const unsigned short* __restrict__ KB,   // bf16 preconverted (may be null)
    const unsigned short* __restrict__ VT,   // bf16 pre-transposed [d][s]
    const unsigned long long* __restrict__ Mb, // packed mask u64, 32/row
    float* __restrict__ O,
    int kbf)
{
    __shared__ alignas(16) unsigned short Ks[2][BK][64];   // 2x16 KB
    __shared__ alignas(16) unsigned short Vt[2][DH][128];  // 2x16 KB

    // XCD-chunked swizzle: nwg=512, 8 XCDs -> each XCD gets 64 contiguous blk
    const int blk0 = blockIdx.x;
    const int blk  = ((blk0 & 7) << 6) | (blk0 >> 3);

    const int b   = blk >> 8;
    const int h   = (blk >> 4) & 15;
    const int qbase = (blk & 15) * BQ;
    const int bh  = b * 16 + h;

    const int tid  = threadIdx.x;
    const int wave = tid >> 6;
    const int lane = tid & 63;
    const int n16  = lane & 15;
    const int quad = lane >> 4;
    const int bq   = quad << 3;          // mask half-word shift
    const int n7   = n16 & 7;

    // reg-staging constants (kbf=0 fallback only)
    const int srow = tid >> 3;
    const int prow = (((srow >> 2) & 1) << 4) | (((srow >> 3) & 3) << 2) | (srow & 3);
    const int vrow = tid >> 4;
    const int kwcol = (((tid & 7) ^ (prow & 7)) << 3);
    const int vwcol = (((tid & 15) ^ vrow) << 3);

    // swizzled read columns (phys; logical granule recovered via ^(row&(ng-1)))
    const int krc0  = ((quad ^ n7) << 3);
    const int krc1  = krc0 ^ 32;
    int vrc[4];
    #pragma unroll
    for (int kc = 0; kc < 4; ++kc) vrc[kc] = (((kc * 4 + quad) ^ n16) << 3);

    // DMA source geometry (kbf=1): linear LDS dest, permuted global source.
    // K: wave covers phys rows [wave*32+c*8, +8), lane l -> row +(l>>3), gran l&7.
    //    phys row pr holds key  (pr>>5)*32 + sigma^-1(pr&31); phys gran g holds
    //    logical granule g^(pr&7).  sigma^-1(p)=((p>>3&1)<<4)|((p>>2&1)<<3)|((p>>4&1)<<2)|(p&3)
    const int kpr  = wave * 32 + (lane >> 3);              // c adds 8
    // V: wave covers phys rows [wave*16+c*4, +4), lane l -> row +(l>>4), gran l&15.
    const int vpr  = wave * 16 + (lane >> 4);              // c adds 4

    // Q fragments (B operand), PRE-SCALED by ZSCALE
    short8 qf[2][2];
    #pragma unroll
    for (int qg = 0; qg < 2; ++qg) {
        const size_t qoff = (size_t)(b * S_LEN + qbase + wave * 32 + qg * 16 + n16) * D_MODEL
                          + h * DH + quad * 8;
        f32x4 a0 = *(const f32x4*)(Q + qoff);
        f32x4 a1 = *(const f32x4*)(Q + qoff + 4);
        f32x4 a2 = *(const f32x4*)(Q + qoff + 32);
        f32x4 a3 = *(const f32x4*)(Q + qoff + 36);
        short8 q0, q1;
        #pragma unroll
        for (int j = 0; j < 4; ++j) {
            q0[j] = (short)f2bf(a0[j] * ZSCALE); q0[4 + j] = (short)f2bf(a1[j] * ZSCALE);
            q1[j] = (short)f2bf(a2[j] * ZSCALE); q1[4 + j] = (short)f2bf(a3[j] * ZSCALE);
        }
        qf[qg][0] = q0; qf[qg][1] = q1;
    }

    const short8 ones = {0x3F80,0x3F80,0x3F80,0x3F80,0x3F80,0x3F80,0x3F80,0x3F80}; // bf16 1.0

    f32x4 o[2][4], o4[2];
    #pragma unroll
    for (int qg = 0; qg < 2; ++qg) {
        #pragma unroll
        for (int dg = 0; dg < 4; ++dg) o[qg][dg] = f32x4{0.f,0.f,0.f,0.f};
        o4[qg] = f32x4{0.f,0.f,0.f,0.f};
    }

    const unsigned long long* mrow[2];
    #pragma unroll
    for (int qg = 0; qg < 2; ++qg)
        mrow[qg] = Mb + (size_t)(b * S_LEN + qbase + wave * 32 + qg * 16 + n16) * 32;

    const size_t kbase = (size_t)(b * S_LEN) * D_MODEL + h * DH;
    const size_t vbase = (size_t)(bh * 64) * S_LEN;

    unsigned long long mwA[2][2], mwB[2][2];

    auto STAGE = [&](int pb, int kb2) {
        if (kbf) {
            // K tile: 4 x 1KB DMA per wave, linear LDS, permuted global source
            #pragma unroll
            for (int c = 0; c < 4; ++c) {
                const int pr  = kpr + c * 8;
                const int prl = pr & 31;
                const int sr  = (((prl >> 3) & 1) << 4) | (((prl >> 2) & 1) << 3)
                              | (((prl >> 4) & 1) << 2) | (prl & 3);
                const int lg  = (lane & 7) ^ (prl & 7);
                const unsigned short* gp = KB + kbase
                    + (size_t)(kb2 + (pr >> 5) * 32 + sr) * D_MODEL + lg * 8;
                __builtin_amdgcn_global_load_lds(
                    (gas1_t)(const void*)gp,
                    (las3_t)(void*)&Ks[pb][wave * 32 + c * 8][0], 16, 0, 0);
            }
            // V tile: 4 x 1KB DMA per wave
            #pragma unroll
            for (int c = 0; c < 4; ++c) {
                const int r  = vpr + c * 4;
                const int lg = (lane & 15) ^ (r & 15);
                const unsigned short* gp = VT + vbase + (size_t)r * S_LEN + kb2 + lg * 8;
                __builtin_amdgcn_global_load_lds(
                    (gas1_t)(const void*)gp,
                    (las3_t)(void*)&Vt[pb][wave * 16 + c * 4][0], 16, 0, 0);
            }
        } else {
            // fallback: f32 K reg-staged + convert; VT reg-staged
            #pragma unroll
            for (int i = 0; i < 4; ++i) {
                const float* kp = K + kbase + (size_t)(kb2 + i * 32 + srow) * D_MODEL + ((tid & 7) << 3);
                f32x4 p0 = *(const f32x4*)kp, p1 = *(const f32x4*)(kp + 4);
                short8 w;
                #pragma unroll
                for (int j = 0; j < 4; ++j) { w[j] = (short)f2bf(p0[j]); w[4 + j] = (short)f2bf(p1[j]); }
                *(short8*)&Ks[pb][prow + 32 * i][kwcol] = w;
                short8 v = *(const short8*)(VT + vbase + (size_t)(vrow + 16 * i) * S_LEN + kb2 + ((tid & 15) << 3));
                *(short8*)&Vt[pb][vrow + 16 * i][vwcol] = v;
            }
        }
    };
    auto LDM = [&](int kb2, unsigned long long (&mw)[2][2]) {
        const int wi = kb2 >> 6;
        #pragma unroll
        for (int qg = 0; qg < 2; ++qg) { mw[qg][0] = mrow[qg][wi]; mw[qg][1] = mrow[qg][wi + 1]; }
    };
    auto MKAM = [&](unsigned long long (&mw)[2][2], unsigned int (&am)[2][4]) {
        #pragma unroll
        for (int qg = 0; qg < 2; ++qg) {
            am[qg][0] = ((unsigned int)mw[qg][0]) >> bq;
            am[qg][1] = ((unsigned int)(mw[qg][0] >> 32)) >> bq;
            am[qg][2] = ((unsigned int)mw[qg][1]) >> bq;
            am[qg][3] = ((unsigned int)(mw[qg][1] >> 32)) >> bq;
        }
    };
    auto COMPUTE = [&](int pb, unsigned int (&am)[2][4]) {
        u32x4 Af[2][4];   // [qg][kc]
        auto QKCT = [&](int ct) {
            short8 kf0 = *(const short8*)&Ks[pb][ct * 16 + n16][krc0];
            short8 kf1 = *(const short8*)&Ks[pb][ct * 16 + n16][krc1];
            f32x4 sA = {0.f,0.f,0.f,0.f}, sB = sA;
            sA = BMM(kf0, qf[0][0], sA); sA = BMM(kf1, qf[0][1], sA);
            sB = BMM(kf0, qf[1][0], sB); sB = BMM(kf1, qf[1][1], sB);
            unsigned int puA[4], puB[4];
            #pragma unroll
            for (int r = 0; r < 4; ++r) {
                puA[r] = __float_as_uint(__builtin_amdgcn_exp2f(sA[r]));
                puB[r] = __float_as_uint(__builtin_amdgcn_exp2f(sB[r]));
            }
            const int sel = ct >> 1, sb = (ct & 1) * 4, kc = ct >> 1, ub = (ct & 1) * 2;
            unsigned int nibA = (am[0][sel] >> sb) & 0xFu;
            unsigned int nibB = (am[1][sel] >> sb) & 0xFu;
            unsigned int m8A = ((nibA * 0x00204081u) & 0x01010101u) * 0xFFu;
            unsigned int m8B = ((nibB * 0x00204081u) & 0x01010101u) * 0xFFu;
            Af[0][kc][ub + 0] = __builtin_amdgcn_perm(puA[1], puA[0], 0x07060302u)
                              & __builtin_amdgcn_perm(0u, m8A, 0x01010000u);
            Af[0][kc][ub + 1] = __builtin_amdgcn_perm(puA[3], puA[2], 0x07060302u)
                              & __builtin_amdgcn_perm(0u, m8A, 0x03030202u);
            Af[1][kc][ub + 0] = __builtin_amdgcn_perm(puB[1], puB[0], 0x07060302u)
                              & __builtin_amdgcn_perm(0u, m8B, 0x01010000u);
            Af[1][kc][ub + 1] = __builtin_amdgcn_perm(puB[3], puB[2], 0x07060302u)
                              & __builtin_amdgcn_perm(0u, m8B, 0x03030202u);
        };
        auto PVKC = [&](int kc) {
            short8 v0 = *(const short8*)&Vt[pb][      n16][vrc[kc]];
            short8 v1 = *(const short8*)&Vt[pb][16 + n16][vrc[kc]];
            short8 v2 = *(const short8*)&Vt[pb][32 + n16][vrc[kc]];
            short8 v3 = *(const short8*)&Vt[pb][48 + n16][vrc[kc]];
            union { u32x4 u; short8 s; } c0, c1;
            c0.u = Af[0][kc]; c1.u = Af[1][kc];
            o[0][0] = BMM(c0.s, v0, o[0][0]); o[0][1] = BMM(c0.s, v1, o[0][1]);
            o[0][2] = BMM(c0.s, v2, o[0][2]); o[0][3] = BMM(c0.s, v3, o[0][3]);
            o4[0]   = BMM(c0.s, ones, o4[0]);
            o[1][0] = BMM(c1.s, v0, o[1][0]); o[1][1] = BMM(c1.s, v1, o[1][1]);
            o[1][2] = BMM(c1.s, v2, o[1][2]); o[1][3] = BMM(c1.s, v3, o[1][3]);
            o4[1]   = BMM(c1.s, ones, o4[1]);
        };
        __builtin_amdgcn_s_setprio(1);
        QKCT(0); QKCT(1); QKCT(2);
        PVKC(0);
        QKCT(3); QKCT(4);
        PVKC(1);
        QKCT(5); QKCT(6);
        PVKC(2);
        QKCT(7);
        PVKC(3);
        __builtin_amdgcn_s_setprio(0);
    };

    // ---- prologue: tile 0 -> buf0 ----
    STAGE(0, 0);
    LDM(0, mwA);
    FULL_BAR();

    // ---- main: 2-unrolled; stage t+1 into the other buffer each body ----
    for (int it = 0; it < 8; ++it) {
        {   // even tile t=2it on buf0
            const int kn = (2 * it + 1) * BK;
            STAGE(1, kn); LDM(kn, mwB);
            unsigned int am[2][4]; MKAM(mwA, am);
            COMPUTE(0, am);
            FULL_BAR();
        }
        {   // odd tile t=2it+1 on buf1
            const int kn = (2 * it + 2) * BK;
            const bool more = kn < S_LEN;
            if (more) { STAGE(0, kn); LDM(kn, mwA); }
            unsigned int am[2][4]; MKAM(mwB, am);
            COMPUTE(1, am);
            if (more) FULL_BAR();
        }
    }

    // epilogue: normalize by MFMA row sums, store f32 (row=quad*4+r, col=n16)
    #pragma unroll
    for (int qg = 0; qg < 2; ++qg) {
        #pragma unroll
        for (int r = 0; r < 4; ++r) {
            float rl = 1.f / o4[qg][r];
            size_t row = (size_t)(b * S_LEN + qbase + wave * 32 + qg * 16 + quad * 4 + r);
            float* op = O + row * D_MODEL + h * DH + n16;
            op[0]  = o[qg][0][r] * rl;
            op[16] = o[qg][1][r] * rl;
            op[32] = o[qg][2][r] * rl;
            op[48] = o[qg][3][r] * rl;
        }
    }
}

extern "C" void kernel_launch(void* const* d_in, const int* in_sizes, int n_in,
                              void* d_out, int out_size, void* d_ws, size_t ws_size,
                              hipStream_t stream) {
    const float* Q = (const float*)d_in[0];
    const float* K = (const float*)d_in[1];
    const float* V = (const float*)d_in[2];
    const int*   M = (const int*)d_in[3];
    float*       O = (float*)d_out;

    const size_t NEL = (size_t)2 * S_LEN * D_MODEL;            // 4,194,304
    const size_t VT_BYTES = NEL * sizeof(unsigned short);      // 8 MB
    const size_t KB_BYTES = NEL * sizeof(unsigned short);      // 8 MB
    const size_t MB_BYTES = (size_t)2 * S_LEN * 32 * 8;        // 1 MB

    if (ws_size >= VT_BYTES + KB_BYTES + MB_BYTES) {           // 17 MB: full precompute
        unsigned short* VT = (unsigned short*)d_ws;
        unsigned short* KB = (unsigned short*)((char*)d_ws + VT_BYTES);
        unsigned long long* Mb = (unsigned long long*)((char*)d_ws + VT_BYTES + KB_BYTES);
        hipLaunchKernelGGL(cvt_fused, dim3(3072), dim3(256), 0, stream, V, M, K, VT, Mb, KB);
        hipLaunchKernelGGL(mha_fwd_v17, dim3(512), dim3(256), 0, stream,
                           Q, K, KB, VT, Mb, O, 1);
    } else {                                                   // 9 MB: inline K convert
        unsigned short* VT = (unsigned short*)d_ws;
        unsigned long long* Mb = (unsigned long long*)((char*)d_ws + VT_BYTES);
        hipLaunchKernelGGL(cvt_fused, dim3(2048), dim3(256), 0, stream, V, M, K, VT, Mb, (unsigned short*)0);
        hipLaunchKernelGGL(mha_fwd_v17, dim3(512), dim3(256), 0, stream,
                           Q, K, (const unsigned short*)0, VT, Mb, O, 0);
    }
}